// Round 6
// baseline (217.059 us; speedup 1.0000x reference)
//
#include <hip/hip_runtime.h>
#include <hip/hip_bf16.h>
#include <math.h>

// ---------------------------------------------------------------------------
// CrossAttention on MI355X (gfx950), bf16 MFMA pipeline, round 6.
//   cast_all: fp32 -> bf16 (one BW-bound pass)
//   proj_qkv: 768 blocks, global_load_lds(16B) staging, chunked LDS layout
//   attn: BQ=128, split-K (2 halves) -> 1024 blocks / 3 per CU,
//         S^T trick, max-free exp2 softmax; writes UNNORMALIZED O + l
//   gemm_out: combine (O0+O1)/(l0+l1) fused into A-staging; B via glds
// ---------------------------------------------------------------------------

typedef __bf16 bf16x8 __attribute__((ext_vector_type(8)));
typedef __bf16 bf16x4 __attribute__((ext_vector_type(4)));
typedef short s16x4 __attribute__((ext_vector_type(4)));
typedef float f32x4 __attribute__((ext_vector_type(4)));

#define QSCALE 0.18033688011112042f  // 0.125 * log2(e)

__device__ __forceinline__ f32x4 mfma32(bf16x8 a, bf16x8 b, f32x4 c) {
  // 16x16x32: A[m=ln][k=qd*8+j], B[n=ln][k=qd*8+j], D: col=ln, row=qd*4+reg
  return __builtin_amdgcn_mfma_f32_16x16x32_bf16(a, b, c, 0, 0, 0);
}
__device__ __forceinline__ f32x4 mfma16(s16x4 a, s16x4 b, f32x4 c) {
  // 16x16x16: A[m=ln][k=qd*4+j], B[n=ln][k=qd*4+j], D: col=ln, row=qd*4+reg
  return __builtin_amdgcn_mfma_f32_16x16x16bf16_1k(a, b, c, 0, 0, 0);
}

// async global->LDS, 16B per lane; LDS dest = wave-uniform base + lane*16.
__device__ __forceinline__ void glds16(const void* g, void* l) {
  __builtin_amdgcn_global_load_lds(
      (const __attribute__((address_space(1))) unsigned int*)g,
      (__attribute__((address_space(3))) unsigned int*)l, 16, 0, 0);
}

// ---------------------------------------------------------------------------
// fp32 -> bf16 cast of all inputs.
// ---------------------------------------------------------------------------
__global__ __launch_bounds__(256) void cast_all(
    const float* __restrict__ x, const float* __restrict__ ctx,
    const float* __restrict__ wq, const float* __restrict__ wk,
    const float* __restrict__ wv, const float* __restrict__ wo,
    __bf16* __restrict__ xb, __bf16* __restrict__ cb,
    __bf16* __restrict__ wqb, __bf16* __restrict__ wkb,
    __bf16* __restrict__ wvb, __bf16* __restrict__ wob) {
  const int B0 = 1048576;   // x
  const int B1 = 2621440;   // +context
  const int B2 = 2686976;   // +Wq
  const int B3 = 2785280;   // +Wk
  const int B4 = 2883584;   // +Wv
  const int B5 = 2949120;   // +Wo
  for (int i = blockIdx.x * blockDim.x + threadIdx.x; i < B5;
       i += gridDim.x * blockDim.x) {
    const float* s;
    __bf16* d;
    int off;
    if (i < B0)      { s = x;   d = xb;  off = i; }
    else if (i < B1) { s = ctx; d = cb;  off = i - B0; }
    else if (i < B2) { s = wq;  d = wqb; off = i - B1; }
    else if (i < B3) { s = wk;  d = wkb; off = i - B2; }
    else if (i < B4) { s = wv;  d = wvb; off = i - B3; }
    else             { s = wo;  d = wob; off = i - B4; }
    float4 f = ((const float4*)s)[off];
    union { __bf16 b[4]; ushort4 u; } cv;
    cv.b[0] = (__bf16)f.x; cv.b[1] = (__bf16)f.y;
    cv.b[2] = (__bf16)f.z; cv.b[3] = (__bf16)f.w;
    ((ushort4*)d)[off] = cv.u;
  }
}

// ---------------------------------------------------------------------------
// 128x128 GEMM body with glds staging.  Chunked LDS: [kgrp][row][8].
// MODE 0 (roles swapped): bf16 out [b,h,tok,d], 8B stores over d
// MODE 1 (natural roles): bf16 out [b,h,d,tok], 8B stores over tok
// ---------------------------------------------------------------------------
template <int MODE>
__device__ __forceinline__ void gemm_body_g(
    const __bf16* __restrict__ A, const __bf16* __restrict__ B,
    __bf16* __restrict__ Cout, int Kd, float scale, int m0, int n0,
    __bf16 (*As)[128][8], __bf16 (*Bs)[128][8]) {
  const int t = threadIdx.x;
  const int w = t >> 6;
  const int lane = t & 63;
  const int ln = lane & 15;
  const int qd = lane >> 4;
  const int wm = (w >> 1) * 64;
  const int wn = (w & 1) * 64;

  f32x4 zero4 = {0.f, 0.f, 0.f, 0.f};
  f32x4 acc[4][4];
#pragma unroll
  for (int i = 0; i < 4; ++i)
#pragma unroll
    for (int j = 0; j < 4; ++j) acc[i][j] = zero4;

  const __bf16* gA0 = A + (size_t)(m0 + lane) * Kd + w * 8;
  const __bf16* gA1 = A + (size_t)(m0 + 64 + lane) * Kd + w * 8;
  const __bf16* gB0 = B + (size_t)(n0 + lane) * Kd + w * 8;
  const __bf16* gB1 = B + (size_t)(n0 + 64 + lane) * Kd + w * 8;

  for (int kc = 0; kc < Kd; kc += 32) {
    __syncthreads();  // prev iteration's frag reads complete
    glds16(gA0 + kc, &As[w][0][0]);
    glds16(gA1 + kc, &As[w][64][0]);
    glds16(gB0 + kc, &Bs[w][0][0]);
    glds16(gB1 + kc, &Bs[w][64][0]);
    __syncthreads();  // drains vmcnt -> LDS valid
    bf16x8 af[4], bfr[4];
#pragma unroll
    for (int i = 0; i < 4; ++i) {
      af[i] = *(const bf16x8*)&As[qd][wm + i * 16 + ln][0];
      bfr[i] = *(const bf16x8*)&Bs[qd][wn + i * 16 + ln][0];
    }
#pragma unroll
    for (int i = 0; i < 4; ++i)
#pragma unroll
      for (int j = 0; j < 4; ++j) {
        if (MODE == 1)
          acc[i][j] = mfma32(af[i], bfr[j], acc[i][j]);  // D: row=tok, col=e
        else
          acc[i][j] = mfma32(bfr[j], af[i], acc[i][j]);  // D: row=e, col=tok
      }
  }

#pragma unroll
  for (int i = 0; i < 4; ++i)
#pragma unroll
    for (int j = 0; j < 4; ++j) {
      if (MODE == 0) {
        const int gm = m0 + wm + i * 16 + ln;           // token
        const int gn0 = n0 + wn + j * 16 + qd * 4;      // e (4 consecutive)
        const int bb = gm >> 11, tok = gm & 2047;
        const int hh = gn0 >> 6, dd0 = gn0 & 63;
        bf16x4 v;
#pragma unroll
        for (int rg = 0; rg < 4; ++rg) v[rg] = (__bf16)(acc[i][j][rg] * scale);
        *(bf16x4*)(Cout + (((size_t)bb * 8 + hh) * 2048 + tok) * 64 + dd0) = v;
      } else {
        const int gm0 = m0 + wm + i * 16 + qd * 4;      // token (4 consecutive)
        const int gn = n0 + wn + j * 16 + ln;           // e
        const int bb = gm0 >> 11, tok0 = gm0 & 2047;
        const int hh = gn >> 6, dd = gn & 63;
        bf16x4 v;
#pragma unroll
        for (int rg = 0; rg < 4; ++rg) v[rg] = (__bf16)acc[i][j][rg];
        *(bf16x4*)(Cout + (((size_t)bb * 8 + hh) * 64 + dd) * 2048 + tok0) = v;
      }
    }
}

// Fused Q/K/V projections: grid (64, 12) = 768 blocks -> 3 blocks/CU.
__global__ __launch_bounds__(256, 3) void proj_qkv(
    const __bf16* __restrict__ xb, const __bf16* __restrict__ cb,
    const __bf16* __restrict__ Wq, const __bf16* __restrict__ Wk,
    const __bf16* __restrict__ Wv, __bf16* __restrict__ Qw,
    __bf16* __restrict__ Kw, __bf16* __restrict__ Vtw) {
  __shared__ __align__(16) __bf16 As[4][128][8];  // 8 KB
  __shared__ __align__(16) __bf16 Bs[4][128][8];  // 8 KB
  const int m0 = blockIdx.x * 128;
  const int job = blockIdx.y >> 2;  // 0=Q, 1=K, 2=V
  const int n0 = (blockIdx.y & 3) * 128;
  if (job == 0)
    gemm_body_g<0>(xb, Wq, Qw, 512, QSCALE, m0, n0, As, Bs);
  else if (job == 1)
    gemm_body_g<0>(cb, Wk, Kw, 768, 1.0f, m0, n0, As, Bs);
  else
    gemm_body_g<1>(cb, Wv, Vtw, 768, 1.0f, m0, n0, As, Bs);
}

// ---------------------------------------------------------------------------
// Final GEMM: out = ((O0+O1)/(l0+l1)) Wo^T + bo, fp32.  64x128 tiles,
// grid (128,4)=512.  Combine+normalize fused into A-staging; B via glds.
// ---------------------------------------------------------------------------
__global__ __launch_bounds__(256) void gemm_out(
    const __bf16* __restrict__ O0,  // unnormalized O, split 0 [8192 x 512]
    const __bf16* __restrict__ O1,  // split 1
    const float* __restrict__ lbuf, // [2][32][2048]
    const __bf16* __restrict__ B,   // Wo bf16 [512 x 512]
    float* __restrict__ C,          // out [8192 x 512] fp32
    const float* __restrict__ bias) {
  const int m0 = blockIdx.x * 64;
  const int n0 = blockIdx.y * 128;
  const int t = threadIdx.x;
  const int w = t >> 6;
  const int lane = t & 63;
  const int ln = lane & 15;
  const int qd = lane >> 4;
  const int wm = (w >> 1) * 32;
  const int wn = (w & 1) * 64;

  __shared__ __align__(16) __bf16 As[64][40];      // padded, manual staging
  __shared__ __align__(16) __bf16 Bs[4][128][8];   // chunked, glds staging

  f32x4 zero4 = {0.f, 0.f, 0.f, 0.f};
  f32x4 acc[2][4];
#pragma unroll
  for (int i = 0; i < 2; ++i)
#pragma unroll
    for (int j = 0; j < 4; ++j) acc[i][j] = zero4;

  const int ra = t >> 2, ca = (t & 3) * 8;  // A staging: 8 elts/thread
  const int gm_s = m0 + ra;
  const int bidx = gm_s >> 11, tok_s = gm_s & 2047;
  const size_t aoff = (size_t)gm_s * 512 + ca;
  const __bf16* gB0 = B + (size_t)(n0 + lane) * 512 + w * 8;
  const __bf16* gB1 = B + (size_t)(n0 + 64 + lane) * 512 + w * 8;

  for (int kc = 0; kc < 512; kc += 32) {
    // combine + normalize A (head hh is uniform across the 32-col block)
    const int hh = kc >> 6;
    const float l0 = lbuf[((size_t)bidx * 8 + hh) * 2048 + tok_s];
    const float l1 = lbuf[(size_t)65536 + ((size_t)bidx * 8 + hh) * 2048 + tok_s];
    const float inv = 1.0f / (l0 + l1);
    union { bf16x8 v; uint4 u; } u0, u1, r;
    u0.u = *(const uint4*)(O0 + aoff + kc);
    u1.u = *(const uint4*)(O1 + aoff + kc);
#pragma unroll
    for (int e = 0; e < 8; ++e)
      r.v[e] = (__bf16)(((float)u0.v[e] + (float)u1.v[e]) * inv);
    __syncthreads();
    glds16(gB0 + kc, &Bs[w][0][0]);
    glds16(gB1 + kc, &Bs[w][64][0]);
    *(uint4*)&As[ra][ca] = r.u;
    __syncthreads();
    bf16x8 af[2], bfr[4];
#pragma unroll
    for (int i = 0; i < 2; ++i)
      af[i] = *(const bf16x8*)&As[wm + i * 16 + ln][qd * 8];
#pragma unroll
    for (int j = 0; j < 4; ++j)
      bfr[j] = *(const bf16x8*)&Bs[qd][wn + j * 16 + ln][0];
#pragma unroll
    for (int i = 0; i < 2; ++i)
#pragma unroll
      for (int j = 0; j < 4; ++j)
        acc[i][j] = mfma32(bfr[j], af[i], acc[i][j]);
  }

#pragma unroll
  for (int i = 0; i < 2; ++i)
#pragma unroll
    for (int j = 0; j < 4; ++j) {
      const int gm = m0 + wm + i * 16 + ln;
      const int gn0 = n0 + wn + j * 16 + qd * 4;
      f32x4 bi = *(const f32x4*)&bias[gn0];
      f32x4 v = acc[i][j] + bi;
      *(f32x4*)&C[(size_t)gm * 512 + gn0] = v;
    }
}

// ---------------------------------------------------------------------------
// Flash attention, S^T, max-free exp2 softmax, BQ=128, SPLIT-K over 2 halves.
// Grid (16, 32, 2) = 1024 blocks, LDS 52.7KB -> 3 blocks/CU.
// Writes UNNORMALIZED O (bf16) per split + row sums l (fp32).
// ---------------------------------------------------------------------------
__global__ __launch_bounds__(256, 3) void attn_kernel(
    const __bf16* __restrict__ Q,   // [BH][2048][64], pre-scaled by QSCALE
    const __bf16* __restrict__ K,   // [BH][2048][64]
    const __bf16* __restrict__ Vt,  // [BH][64][2048]
    __bf16* __restrict__ Oh,        // [2][B][2048][512] unnormalized
    float* __restrict__ lbuf) {     // [2][BH][2048]
  const int S = 2048;
  const int qt = blockIdx.x;
  const int bh = blockIdx.y;
  const int sp = blockIdx.z;
  const int b = bh >> 3, h = bh & 7;
  const int t = threadIdx.x;
  const int w = t >> 6;
  const int lane = t & 63;
  const int ln = lane & 15;
  const int qd = lane >> 4;

  __shared__ __align__(16) __bf16 Qs[128][68];   // 17408B
  __shared__ __align__(16) __bf16 Ks[128][72];   // 18432B
  __shared__ __align__(16) __bf16 Vts[64][132];  // 16896B  total 52736B

  // ---- stage Q once: 32 elts/thread (4x uint4 load, 8x uint2 store)
  {
    const int r = t >> 1, c = (t & 1) * 32;
    const uint4* g =
        (const uint4*)(Q + ((size_t)bh * S + qt * 128 + r) * 64 + c);
    uint4 q0 = g[0], q1 = g[1], q2 = g[2], q3 = g[3];
    uint2* d = (uint2*)&Qs[r][c];
    d[0] = *(uint2*)&q0; d[1] = *((uint2*)&q0 + 1);
    d[2] = *(uint2*)&q1; d[3] = *((uint2*)&q1 + 1);
    d[4] = *(uint2*)&q2; d[5] = *((uint2*)&q2 + 1);
    d[6] = *(uint2*)&q3; d[7] = *((uint2*)&q3 + 1);
  }

  f32x4 zero4 = {0.f, 0.f, 0.f, 0.f};
  f32x4 o[2][4];  // o[mt][i]: D[row=d=i*16+qd*4+rg][col=Qrow=ln]
#pragma unroll
  for (int mt = 0; mt < 2; ++mt)
#pragma unroll
    for (int i = 0; i < 4; ++i) o[mt][i] = zero4;
  float lrow[2] = {0.f, 0.f};

  const int kr = t >> 1, kc = (t & 1) * 32;
  const int vd = t >> 2, vc = (t & 3) * 32;
  const int kt0 = sp * 8;

  for (int kt = kt0; kt < kt0 + 8; ++kt) {
    const uint4* gK =
        (const uint4*)(K + ((size_t)bh * S + kt * 128 + kr) * 64 + kc);
    const uint4* gV =
        (const uint4*)(Vt + ((size_t)bh * 64 + vd) * S + kt * 128 + vc);
    uint4 kv0 = gK[0], kv1 = gK[1], kv2 = gK[2], kv3 = gK[3];
    uint4 vv0 = gV[0], vv1 = gV[1], vv2 = gV[2], vv3 = gV[3];
    __syncthreads();
    {
      uint4* dK = (uint4*)&Ks[kr][kc];  // 144B stride: 16B-aligned
      dK[0] = kv0; dK[1] = kv1; dK[2] = kv2; dK[3] = kv3;
      uint2* dV = (uint2*)&Vts[vd][vc];  // 264B stride: 8B-aligned
      dV[0] = *(uint2*)&vv0; dV[1] = *((uint2*)&vv0 + 1);
      dV[2] = *(uint2*)&vv1; dV[3] = *((uint2*)&vv1 + 1);
      dV[4] = *(uint2*)&vv2; dV[5] = *((uint2*)&vv2 + 1);
      dV[6] = *(uint2*)&vv3; dV[7] = *((uint2*)&vv3 + 1);
    }
    __syncthreads();

    // ---- St = K Q^T
    f32x4 s[2][8];
#pragma unroll
    for (int mt = 0; mt < 2; ++mt)
#pragma unroll
      for (int nt = 0; nt < 8; ++nt) s[mt][nt] = zero4;
#pragma unroll
    for (int kst = 0; kst < 2; ++kst) {
      bf16x8 bq[2];
#pragma unroll
      for (int mt = 0; mt < 2; ++mt) {
        union { bf16x4 hh[2]; bf16x8 v; } u;
        u.hh[0] = *(const bf16x4*)&Qs[w * 32 + mt * 16 + ln][kst * 32 + qd * 8];
        u.hh[1] =
            *(const bf16x4*)&Qs[w * 32 + mt * 16 + ln][kst * 32 + qd * 8 + 4];
        bq[mt] = u.v;
      }
#pragma unroll
      for (int nt = 0; nt < 8; ++nt) {
        bf16x8 ak = *(const bf16x8*)&Ks[nt * 16 + ln][kst * 32 + qd * 8];
        s[0][nt] = mfma32(ak, bq[0], s[0][nt]);
        s[1][nt] = mfma32(ak, bq[1], s[1][nt]);
      }
    }

    // ---- max-free softmax: P = 2^s
#pragma unroll
    for (int mt = 0; mt < 2; ++mt) {
      float rs = 0.f;
#pragma unroll
      for (int nt = 0; nt < 8; ++nt)
#pragma unroll
        for (int rg = 0; rg < 4; ++rg) {
          float p = exp2f(s[mt][nt][rg]);
          s[mt][nt][rg] = p;
          rs += p;
        }
      lrow[mt] += rs;
    }

    // ---- O^T += Vt P^T : P straight from registers
#pragma unroll
    for (int nt = 0; nt < 8; ++nt) {
      s16x4 p0, p1;
      {
        bf16x4 c0, c1;
#pragma unroll
        for (int rg = 0; rg < 4; ++rg) {
          c0[rg] = (__bf16)s[0][nt][rg];
          c1[rg] = (__bf16)s[1][nt][rg];
        }
        p0 = __builtin_bit_cast(s16x4, c0);
        p1 = __builtin_bit_cast(s16x4, c1);
      }
#pragma unroll
      for (int i = 0; i < 4; ++i) {
        bf16x4 av = *(const bf16x4*)&Vts[i * 16 + ln][nt * 16 + qd * 4];
        s16x4 a = __builtin_bit_cast(s16x4, av);
        o[0][i] = mfma16(a, p0, o[0][i]);
        o[1][i] = mfma16(a, p1, o[1][i]);
      }
    }
  }

  // ---- epilogue: write UNNORMALIZED O + l (combine happens in gemm_out)
  __bf16* Osp = Oh + (size_t)sp * 8192 * 512;
#pragma unroll
  for (int mt = 0; mt < 2; ++mt) {
    float l = lrow[mt];
    l += __shfl_xor(l, 16);
    l += __shfl_xor(l, 32);
    const int tok = qt * 128 + w * 32 + mt * 16 + ln;
    if (qd == 0) lbuf[((size_t)sp * 32 + bh) * 2048 + tok] = l;
#pragma unroll
    for (int i = 0; i < 4; ++i) {
      bf16x4 v;
#pragma unroll
      for (int rg = 0; rg < 4; ++rg) v[rg] = (__bf16)o[mt][i][rg];
      const int col = h * 64 + i * 16 + qd * 4;
      *(bf16x4*)&Osp[((size_t)b * S + tok) * 512 + col] = v;
    }
  }
}

// ---------------------------------------------------------------------------
extern "C" void kernel_launch(void* const* d_in, const int* in_sizes, int n_in,
                              void* d_out, int out_size, void* d_ws,
                              size_t ws_size, hipStream_t stream) {
  const float* x = (const float*)d_in[0];
  const float* ctx = (const float*)d_in[1];
  const float* Wq = (const float*)d_in[2];
  const float* Wk = (const float*)d_in[3];
  const float* Wv = (const float*)d_in[4];
  const float* Wo = (const float*)d_in[5];
  const float* bo = (const float*)d_in[6];

  char* p = (char*)d_ws;
  __bf16* xb = (__bf16*)p;   p += (size_t)8192 * 512 * 2;
  __bf16* cb = (__bf16*)p;   p += (size_t)8192 * 768 * 2;
  __bf16* wqb = (__bf16*)p;  p += (size_t)512 * 512 * 2;
  __bf16* wkb = (__bf16*)p;  p += (size_t)512 * 768 * 2;
  __bf16* wvb = (__bf16*)p;  p += (size_t)512 * 768 * 2;
  __bf16* wob = (__bf16*)p;  p += (size_t)512 * 512 * 2;
  __bf16* Qw = (__bf16*)p;   p += (size_t)8192 * 512 * 2;
  __bf16* Kw = (__bf16*)p;   p += (size_t)8192 * 512 * 2;
  __bf16* Vtw = (__bf16*)p;  p += (size_t)8192 * 512 * 2;
  __bf16* Oh = (__bf16*)p;   p += (size_t)2 * 8192 * 512 * 2;
  float* lbuf = (float*)p;   p += (size_t)2 * 32 * 2048 * 4;

  cast_all<<<2880, 256, 0, stream>>>(x, ctx, Wq, Wk, Wv, Wo, xb, cb, wqb, wkb,
                                     wvb, wob);

  dim3 gp(64, 12);
  proj_qkv<<<gp, 256, 0, stream>>>(xb, cb, wqb, wkb, wvb, Qw, Kw, Vtw);

  dim3 ga(16, 32, 2);
  attn_kernel<<<ga, 256, 0, stream>>>(Qw, Kw, Vtw, Oh, lbuf);

  dim3 go(128, 4);
  gemm_out<<<go, 256, 0, stream>>>(Oh, Oh + (size_t)8192 * 512, lbuf, wob,
                                   (float*)d_out, bo);
}

// Round 7
// 206.391 us; speedup vs baseline: 1.0517x; 1.0517x over previous
//
#include <hip/hip_runtime.h>
#include <hip/hip_bf16.h>
#include <math.h>

// ---------------------------------------------------------------------------
// CrossAttention on MI355X (gfx950), bf16 MFMA pipeline, round 7.
//   cast_all: fp32 -> bf16 (BW-bound pass)
//   proj_qkv: R5-style manual staging (loads issued before barrier),
//             MODE 1 writes V^T with WITHIN-32-TOKEN PERMUTATION so attn's
//             PV fragments are contiguous b128 reads.
//   attn: BQ=128, split-K=2 (1024 blocks), Q IN REGISTERS (no Qs LDS),
//         LDS 35.8KB -> 4 blocks/CU, per-pair QK->exp2->PV fusion
//         (score footprint 16 regs), writes unnormalized O + l.
//   gemm_out: combine (O0+O1)*inv(l0+l1) fused in A-staging, inv hoisted.
// ---------------------------------------------------------------------------

typedef __bf16 bf16x8 __attribute__((ext_vector_type(8)));
typedef __bf16 bf16x4 __attribute__((ext_vector_type(4)));
typedef short s16x4 __attribute__((ext_vector_type(4)));
typedef float f32x4 __attribute__((ext_vector_type(4)));

#define QSCALE 0.18033688011112042f  // 0.125 * log2(e)

__device__ __forceinline__ f32x4 mfma32(bf16x8 a, bf16x8 b, f32x4 c) {
  // 16x16x32: A[m=ln][k=qd*8+j], B[n=ln][k=qd*8+j], D: col=ln, row=qd*4+reg
  return __builtin_amdgcn_mfma_f32_16x16x32_bf16(a, b, c, 0, 0, 0);
}
__device__ __forceinline__ f32x4 mfma16(s16x4 a, s16x4 b, f32x4 c) {
  // 16x16x16: A[m=ln][k=qd*4+j], B[n=ln][k=qd*4+j], D: col=ln, row=qd*4+reg
  return __builtin_amdgcn_mfma_f32_16x16x16bf16_1k(a, b, c, 0, 0, 0);
}

// ---------------------------------------------------------------------------
// fp32 -> bf16 cast of all inputs.
// ---------------------------------------------------------------------------
__global__ __launch_bounds__(256) void cast_all(
    const float* __restrict__ x, const float* __restrict__ ctx,
    const float* __restrict__ wq, const float* __restrict__ wk,
    const float* __restrict__ wv, const float* __restrict__ wo,
    __bf16* __restrict__ xb, __bf16* __restrict__ cb,
    __bf16* __restrict__ wqb, __bf16* __restrict__ wkb,
    __bf16* __restrict__ wvb, __bf16* __restrict__ wob) {
  const int B0 = 1048576;
  const int B1 = 2621440;
  const int B2 = 2686976;
  const int B3 = 2785280;
  const int B4 = 2883584;
  const int B5 = 2949120;
  for (int i = blockIdx.x * blockDim.x + threadIdx.x; i < B5;
       i += gridDim.x * blockDim.x) {
    const float* s;
    __bf16* d;
    int off;
    if (i < B0)      { s = x;   d = xb;  off = i; }
    else if (i < B1) { s = ctx; d = cb;  off = i - B0; }
    else if (i < B2) { s = wq;  d = wqb; off = i - B1; }
    else if (i < B3) { s = wk;  d = wkb; off = i - B2; }
    else if (i < B4) { s = wv;  d = wvb; off = i - B3; }
    else             { s = wo;  d = wob; off = i - B4; }
    float4 f = ((const float4*)s)[off];
    union { __bf16 b[4]; ushort4 u; } cv;
    cv.b[0] = (__bf16)f.x; cv.b[1] = (__bf16)f.y;
    cv.b[2] = (__bf16)f.z; cv.b[3] = (__bf16)f.w;
    ((ushort4*)d)[off] = cv.u;
  }
}

// ---------------------------------------------------------------------------
// 128x128 GEMM body, manual staging (loads before barrier), bf16 inputs.
// MODE 0 (roles swapped): bf16 out [b,h,tok,d], 8B stores over d
// MODE 1 (natural roles): bf16 out [b,h,d,tokPERM]; tokens permuted within
//         32-token chunks: local u = e*16+qd*4+rg  ->  u' = qd*8+e*4+rg
// ---------------------------------------------------------------------------
template <int MODE>
__device__ __forceinline__ void gemm_body(
    const __bf16* __restrict__ A, const __bf16* __restrict__ B,
    __bf16* __restrict__ Cout, int Kd, float scale, int m0, int n0,
    __bf16 (*As)[40], __bf16 (*Bs)[40]) {
  const int t = threadIdx.x;
  const int w = t >> 6;
  const int lane = t & 63;
  const int ln = lane & 15;
  const int qd = lane >> 4;
  const int wm = (w >> 1) * 64;
  const int wn = (w & 1) * 64;

  f32x4 zero4 = {0.f, 0.f, 0.f, 0.f};
  f32x4 acc[4][4];
#pragma unroll
  for (int i = 0; i < 4; ++i)
#pragma unroll
    for (int j = 0; j < 4; ++j) acc[i][j] = zero4;

  const int r = t >> 1;
  const int c0 = (t & 1) * 16;
  const __bf16* gA = A + (size_t)(m0 + r) * Kd + c0;
  const __bf16* gB = B + (size_t)(n0 + r) * Kd + c0;

  for (int kc = 0; kc < Kd; kc += 32) {
    uint4 a0 = *(const uint4*)(gA + kc);
    uint4 a1 = *(const uint4*)(gA + kc + 8);
    uint4 b0 = *(const uint4*)(gB + kc);
    uint4 b1 = *(const uint4*)(gB + kc + 8);
    __syncthreads();
    *(uint4*)&As[r][c0] = a0;
    *(uint4*)&As[r][c0 + 8] = a1;
    *(uint4*)&Bs[r][c0] = b0;
    *(uint4*)&Bs[r][c0 + 8] = b1;
    __syncthreads();
    bf16x8 af[4], bfr[4];
#pragma unroll
    for (int i = 0; i < 4; ++i) {
      af[i] = *(const bf16x8*)&As[wm + i * 16 + ln][qd * 8];
      bfr[i] = *(const bf16x8*)&Bs[wn + i * 16 + ln][qd * 8];
    }
#pragma unroll
    for (int i = 0; i < 4; ++i)
#pragma unroll
      for (int j = 0; j < 4; ++j) {
        if (MODE == 1)
          acc[i][j] = mfma32(af[i], bfr[j], acc[i][j]);  // D: row=tok, col=e
        else
          acc[i][j] = mfma32(bfr[j], af[i], acc[i][j]);  // D: row=e, col=tok
      }
  }

#pragma unroll
  for (int i = 0; i < 4; ++i)
#pragma unroll
    for (int j = 0; j < 4; ++j) {
      if (MODE == 0) {
        const int gm = m0 + wm + i * 16 + ln;           // token
        const int gn0 = n0 + wn + j * 16 + qd * 4;      // e (4 consecutive)
        const int bb = gm >> 11, tok = gm & 2047;
        const int hh = gn0 >> 6, dd0 = gn0 & 63;
        bf16x4 v;
#pragma unroll
        for (int rg = 0; rg < 4; ++rg) v[rg] = (__bf16)(acc[i][j][rg] * scale);
        *(bf16x4*)(Cout + (((size_t)bb * 8 + hh) * 2048 + tok) * 64 + dd0) = v;
      } else {
        const int gm0 = m0 + wm + i * 16 + qd * 4;      // token (4 consecutive)
        const int gn = n0 + wn + j * 16 + ln;           // e
        const int bb = gm0 >> 11;
        const int tokbase = (gm0 & 2047) & ~31;         // 32-token chunk base
        const int up = qd * 8 + (i & 1) * 4;            // permuted offset
        const int hh = gn >> 6, dd = gn & 63;
        bf16x4 v;
#pragma unroll
        for (int rg = 0; rg < 4; ++rg) v[rg] = (__bf16)acc[i][j][rg];
        *(bf16x4*)(Cout + (((size_t)bb * 8 + hh) * 64 + dd) * 2048 + tokbase +
                   up) = v;
      }
    }
}

// Fused Q/K/V projections: grid (64, 12) = 768 blocks -> 3 blocks/CU.
__global__ __launch_bounds__(256, 3) void proj_qkv(
    const __bf16* __restrict__ xb, const __bf16* __restrict__ cb,
    const __bf16* __restrict__ Wq, const __bf16* __restrict__ Wk,
    const __bf16* __restrict__ Wv, __bf16* __restrict__ Qw,
    __bf16* __restrict__ Kw, __bf16* __restrict__ Vtw) {
  __shared__ __bf16 As[128][40];
  __shared__ __bf16 Bs[128][40];
  const int m0 = blockIdx.x * 128;
  const int job = blockIdx.y >> 2;  // 0=Q, 1=K, 2=V
  const int n0 = (blockIdx.y & 3) * 128;
  if (job == 0)
    gemm_body<0>(xb, Wq, Qw, 512, QSCALE, m0, n0, As, Bs);
  else if (job == 1)
    gemm_body<0>(cb, Wk, Kw, 768, 1.0f, m0, n0, As, Bs);
  else
    gemm_body<1>(cb, Wv, Vtw, 768, 1.0f, m0, n0, As, Bs);
}

// ---------------------------------------------------------------------------
// Final GEMM: out = ((O0+O1)/(l0+l1)) Wo^T + bo, fp32.  64x128 tiles,
// grid (128,4)=512.  inv(l) hoisted out of the (fully unrolled) k-loop.
// ---------------------------------------------------------------------------
__global__ __launch_bounds__(256) void gemm_out(
    const __bf16* __restrict__ O0, const __bf16* __restrict__ O1,
    const float* __restrict__ lbuf,  // [2][32][2048]
    const __bf16* __restrict__ B,    // Wo bf16 [512 x 512]
    float* __restrict__ C, const float* __restrict__ bias) {
  const int m0 = blockIdx.x * 64;
  const int n0 = blockIdx.y * 128;
  const int t = threadIdx.x;
  const int w = t >> 6;
  const int lane = t & 63;
  const int ln = lane & 15;
  const int qd = lane >> 4;
  const int wm = (w >> 1) * 32;
  const int wn = (w & 1) * 64;

  __shared__ __bf16 As[64][40];
  __shared__ __bf16 Bs[128][40];

  f32x4 zero4 = {0.f, 0.f, 0.f, 0.f};
  f32x4 acc[2][4];
#pragma unroll
  for (int i = 0; i < 2; ++i)
#pragma unroll
    for (int j = 0; j < 4; ++j) acc[i][j] = zero4;

  const int ra = t >> 2, ca = (t & 3) * 8;
  const int rb = t >> 1, cb = (t & 1) * 16;
  const int gm_s = m0 + ra;
  const int bidx = gm_s >> 11, tok_s = gm_s & 2047;
  const size_t aoff = (size_t)gm_s * 512 + ca;
  const __bf16* gB = B + (size_t)(n0 + rb) * 512 + cb;

  // hoist the split-l combine out of the k-loop
  float inv[8];
#pragma unroll
  for (int hh = 0; hh < 8; ++hh) {
    const float l0 = lbuf[((size_t)bidx * 8 + hh) * 2048 + tok_s];
    const float l1 = lbuf[65536 + ((size_t)bidx * 8 + hh) * 2048 + tok_s];
    inv[hh] = 1.0f / (l0 + l1);
  }

#pragma unroll
  for (int kc = 0; kc < 512; kc += 32) {
    const float iv = inv[kc >> 6];
    union { bf16x8 v; uint4 u; } u0, u1, rr;
    u0.u = *(const uint4*)(O0 + aoff + kc);
    u1.u = *(const uint4*)(O1 + aoff + kc);
    uint4 b0 = *(const uint4*)(gB + kc);
    uint4 b1 = *(const uint4*)(gB + kc + 8);
#pragma unroll
    for (int e = 0; e < 8; ++e)
      rr.v[e] = (__bf16)(((float)u0.v[e] + (float)u1.v[e]) * iv);
    __syncthreads();
    *(uint4*)&As[ra][ca] = rr.u;
    *(uint4*)&Bs[rb][cb] = b0;
    *(uint4*)&Bs[rb][cb + 8] = b1;
    __syncthreads();
    bf16x8 af[2], bfr[4];
#pragma unroll
    for (int i = 0; i < 2; ++i)
      af[i] = *(const bf16x8*)&As[wm + i * 16 + ln][qd * 8];
#pragma unroll
    for (int j = 0; j < 4; ++j)
      bfr[j] = *(const bf16x8*)&Bs[wn + j * 16 + ln][qd * 8];
#pragma unroll
    for (int i = 0; i < 2; ++i)
#pragma unroll
      for (int j = 0; j < 4; ++j)
        acc[i][j] = mfma32(bfr[j], af[i], acc[i][j]);
  }

#pragma unroll
  for (int i = 0; i < 2; ++i)
#pragma unroll
    for (int j = 0; j < 4; ++j) {
      const int gm = m0 + wm + i * 16 + ln;
      const int gn0 = n0 + wn + j * 16 + qd * 4;
      f32x4 bi = *(const f32x4*)&bias[gn0];
      f32x4 v = acc[i][j] + bi;
      *(f32x4*)&C[(size_t)gm * 512 + gn0] = v;
    }
}

// ---------------------------------------------------------------------------
// Flash attention: S^T trick, exp2 max-free softmax, BQ=128, split-K=2.
// Q kept in registers (no Qs LDS).  LDS = Ks 18.4KB + Vts 17.4KB = 35.8KB
// -> 4 blocks/CU; per-pair QK->exp->PV fusion keeps VGPR <= 128.
// Vt global layout is TOKEN-PERMUTED within 32-chunks (see proj MODE 1):
// PV A-frags for an nt-pair are one contiguous b128.
// ---------------------------------------------------------------------------
__global__ __launch_bounds__(256, 4) void attn_kernel(
    const __bf16* __restrict__ Q,   // [BH][2048][64], pre-scaled by QSCALE
    const __bf16* __restrict__ K,   // [BH][2048][64]
    const __bf16* __restrict__ Vt,  // [BH][64][2048-permuted]
    __bf16* __restrict__ Oh,        // [2][B][2048][512] unnormalized
    float* __restrict__ lbuf) {     // [2][BH][2048]
  const int S = 2048;
  const int qt = blockIdx.x;
  const int bh = blockIdx.y;
  const int sp = blockIdx.z;
  const int b = bh >> 3, h = bh & 7;
  const int t = threadIdx.x;
  const int w = t >> 6;
  const int lane = t & 63;
  const int ln = lane & 15;
  const int qd = lane >> 4;

  __shared__ __align__(16) __bf16 Ks[128][72];   // 18432B
  __shared__ __align__(16) __bf16 Vts[64][136];  // 17408B  total 35840B

  // ---- Q fragments in registers (wave w owns Q rows w*32 .. w*32+31)
  bf16x8 bq[2][2];  // [mt][kst]
  {
    const __bf16* qb =
        Q + ((size_t)bh * S + qt * 128 + w * 32 + ln) * 64 + qd * 8;
#pragma unroll
    for (int mt = 0; mt < 2; ++mt)
#pragma unroll
      for (int kst = 0; kst < 2; ++kst)
        bq[mt][kst] = *(const bf16x8*)(qb + mt * 1024 + kst * 32);
  }

  f32x4 zero4 = {0.f, 0.f, 0.f, 0.f};
  f32x4 o[2][4];  // o[mt][i]: D[row=d=i*16+qd*4+rg][col=Qrow=ln]
#pragma unroll
  for (int mt = 0; mt < 2; ++mt)
#pragma unroll
    for (int i = 0; i < 4; ++i) o[mt][i] = zero4;
  float lrow[2] = {0.f, 0.f};

  const int kr = t >> 1, kc = (t & 1) * 32;  // K staging map
  const int vd = t >> 2, vc = (t & 3) * 32;  // Vt staging map
  const int kt0 = sp * 8;

  for (int kt = kt0; kt < kt0 + 8; ++kt) {
    const uint4* gK =
        (const uint4*)(K + ((size_t)bh * S + kt * 128 + kr) * 64 + kc);
    const uint4* gV =
        (const uint4*)(Vt + ((size_t)bh * 64 + vd) * S + kt * 128 + vc);
    uint4 kv0 = gK[0], kv1 = gK[1], kv2 = gK[2], kv3 = gK[3];
    uint4 vv0 = gV[0], vv1 = gV[1], vv2 = gV[2], vv3 = gV[3];
    __syncthreads();
    {
      uint4* dK = (uint4*)&Ks[kr][kc];   // 144B stride: 16B-aligned
      dK[0] = kv0; dK[1] = kv1; dK[2] = kv2; dK[3] = kv3;
      uint4* dV = (uint4*)&Vts[vd][vc];  // 272B stride: 16B-aligned
      dV[0] = vv0; dV[1] = vv1; dV[2] = vv2; dV[3] = vv3;
    }
    __syncthreads();

    // ---- per nt-pair: QK (mfma32) -> exp2 -> PV (mfma16)
#pragma unroll
    for (int c = 0; c < 4; ++c) {
      // V fragments: one b128 per (i): {nt=2c: rg0..3, nt=2c+1: rg0..3}
      bf16x8 av[4];
#pragma unroll
      for (int i = 0; i < 4; ++i)
        av[i] = *(const bf16x8*)&Vts[i * 16 + ln][c * 32 + qd * 8];

      f32x4 s[2][2];  // [e][mt]
      s[0][0] = zero4; s[0][1] = zero4; s[1][0] = zero4; s[1][1] = zero4;
#pragma unroll
      for (int e = 0; e < 2; ++e) {
        const int nt = c * 2 + e;
#pragma unroll
        for (int kst = 0; kst < 2; ++kst) {
          bf16x8 ak = *(const bf16x8*)&Ks[nt * 16 + ln][kst * 32 + qd * 8];
          s[e][0] = mfma32(ak, bq[0][kst], s[e][0]);
          s[e][1] = mfma32(ak, bq[1][kst], s[e][1]);
        }
      }
      // softmax pieces (max-free): P = 2^s
#pragma unroll
      for (int e = 0; e < 2; ++e)
#pragma unroll
        for (int mt = 0; mt < 2; ++mt) {
          float rs = 0.f;
#pragma unroll
          for (int rg = 0; rg < 4; ++rg) {
            float p = exp2f(s[e][mt][rg]);
            s[e][mt][rg] = p;
            rs += p;
          }
          lrow[mt] += rs;
        }
      // PV
#pragma unroll
      for (int e = 0; e < 2; ++e) {
        bf16x4 c0, c1;
#pragma unroll
        for (int rg = 0; rg < 4; ++rg) {
          c0[rg] = (__bf16)s[e][0][rg];
          c1[rg] = (__bf16)s[e][1][rg];
        }
        s16x4 p0 = __builtin_bit_cast(s16x4, c0);
        s16x4 p1 = __builtin_bit_cast(s16x4, c1);
#pragma unroll
        for (int i = 0; i < 4; ++i) {
          union { bf16x8 v; bf16x4 hh[2]; } U;
          U.v = av[i];
          s16x4 a = __builtin_bit_cast(s16x4, U.hh[e]);
          o[0][i] = mfma16(a, p0, o[0][i]);
          o[1][i] = mfma16(a, p1, o[1][i]);
        }
      }
    }
  }

  // ---- epilogue: write UNNORMALIZED O + l (combine happens in gemm_out)
  __bf16* Osp = Oh + (size_t)sp * 8192 * 512;
#pragma unroll
  for (int mt = 0; mt < 2; ++mt) {
    float l = lrow[mt];
    l += __shfl_xor(l, 16);
    l += __shfl_xor(l, 32);
    const int tok = qt * 128 + w * 32 + mt * 16 + ln;
    if (qd == 0) lbuf[((size_t)sp * 32 + bh) * 2048 + tok] = l;
#pragma unroll
    for (int i = 0; i < 4; ++i) {
      bf16x4 v;
#pragma unroll
      for (int rg = 0; rg < 4; ++rg) v[rg] = (__bf16)o[mt][i][rg];
      const int col = h * 64 + i * 16 + qd * 4;
      *(bf16x4*)&Osp[((size_t)b * S + tok) * 512 + col] = v;
    }
  }
}

// ---------------------------------------------------------------------------
extern "C" void kernel_launch(void* const* d_in, const int* in_sizes, int n_in,
                              void* d_out, int out_size, void* d_ws,
                              size_t ws_size, hipStream_t stream) {
  const float* x = (const float*)d_in[0];
  const float* ctx = (const float*)d_in[1];
  const float* Wq = (const float*)d_in[2];
  const float* Wk = (const float*)d_in[3];
  const float* Wv = (const float*)d_in[4];
  const float* Wo = (const float*)d_in[5];
  const float* bo = (const float*)d_in[6];

  char* p = (char*)d_ws;
  __bf16* xb = (__bf16*)p;   p += (size_t)8192 * 512 * 2;
  __bf16* cb = (__bf16*)p;   p += (size_t)8192 * 768 * 2;
  __bf16* wqb = (__bf16*)p;  p += (size_t)512 * 512 * 2;
  __bf16* wkb = (__bf16*)p;  p += (size_t)512 * 768 * 2;
  __bf16* wvb = (__bf16*)p;  p += (size_t)512 * 768 * 2;
  __bf16* wob = (__bf16*)p;  p += (size_t)512 * 512 * 2;
  __bf16* Qw = (__bf16*)p;   p += (size_t)8192 * 512 * 2;
  __bf16* Kw = (__bf16*)p;   p += (size_t)8192 * 512 * 2;
  __bf16* Vtw = (__bf16*)p;  p += (size_t)8192 * 512 * 2;
  __bf16* Oh = (__bf16*)p;   p += (size_t)2 * 8192 * 512 * 2;
  float* lbuf = (float*)p;   p += (size_t)2 * 32 * 2048 * 4;

  cast_all<<<2880, 256, 0, stream>>>(x, ctx, Wq, Wk, Wv, Wo, xb, cb, wqb, wkb,
                                     wvb, wob);

  dim3 gp(64, 12);
  proj_qkv<<<gp, 256, 0, stream>>>(xb, cb, wqb, wkb, wvb, Qw, Kw, Vtw);

  dim3 ga(16, 32, 2);
  attn_kernel<<<ga, 256, 0, stream>>>(Qw, Kw, Vtw, Oh, lbuf);

  dim3 go(128, 4);
  gemm_out<<<go, 256, 0, stream>>>(Oh, Oh + (size_t)8192 * 512, lbuf, wob,
                                   (float*)d_out, bo);
}

// Round 8
// 204.008 us; speedup vs baseline: 1.0640x; 1.0117x over previous
//
#include <hip/hip_runtime.h>
#include <hip/hip_bf16.h>
#include <math.h>

// ---------------------------------------------------------------------------
// CrossAttention on MI355X (gfx950), bf16 MFMA pipeline, round 8.
//   cast_all: fp32 -> bf16 (BW-bound pass)
//   proj_qkv: glds(16B) + LDS DOUBLE-BUFFER, single barrier per k-step
//   attn: BQ=128 split-K=2, Q in regs, S^T trick, raw v_exp_f32 softmax,
//         V-ones MFMA row-sum (no VALU l-accumulation, no epilogue shuffles)
//   gemm_out: single-barrier pipeline; A=combine((O0+O1)*inv) manual dbuf,
//             B via glds dbuf
// ---------------------------------------------------------------------------

typedef __bf16 bf16x8 __attribute__((ext_vector_type(8)));
typedef __bf16 bf16x4 __attribute__((ext_vector_type(4)));
typedef short s16x4 __attribute__((ext_vector_type(4)));
typedef float f32x4 __attribute__((ext_vector_type(4)));

#define QSCALE 0.18033688011112042f  // 0.125 * log2(e)

#if __has_builtin(__builtin_amdgcn_exp2f)
#define EXP2(x) __builtin_amdgcn_exp2f(x)
#else
#define EXP2(x) exp2f(x)
#endif

__device__ __forceinline__ f32x4 mfma32(bf16x8 a, bf16x8 b, f32x4 c) {
  // 16x16x32: A[m=ln][k=qd*8+j], B[n=ln][k=qd*8+j], D: col=ln, row=qd*4+reg
  return __builtin_amdgcn_mfma_f32_16x16x32_bf16(a, b, c, 0, 0, 0);
}
__device__ __forceinline__ f32x4 mfma16(s16x4 a, s16x4 b, f32x4 c) {
  // 16x16x16: A[m=ln][k=qd*4+j], B[n=ln][k=qd*4+j], D: col=ln, row=qd*4+reg
  return __builtin_amdgcn_mfma_f32_16x16x16bf16_1k(a, b, c, 0, 0, 0);
}

// async global->LDS, 16B/lane; LDS dest = wave-uniform base + lane*16.
__device__ __forceinline__ void glds16(const void* g, void* l) {
  __builtin_amdgcn_global_load_lds(
      (const __attribute__((address_space(1))) unsigned int*)g,
      (__attribute__((address_space(3))) unsigned int*)l, 16, 0, 0);
}

// ---------------------------------------------------------------------------
// fp32 -> bf16 cast of all inputs.
// ---------------------------------------------------------------------------
__global__ __launch_bounds__(256) void cast_all(
    const float* __restrict__ x, const float* __restrict__ ctx,
    const float* __restrict__ wq, const float* __restrict__ wk,
    const float* __restrict__ wv, const float* __restrict__ wo,
    __bf16* __restrict__ xb, __bf16* __restrict__ cb,
    __bf16* __restrict__ wqb, __bf16* __restrict__ wkb,
    __bf16* __restrict__ wvb, __bf16* __restrict__ wob) {
  const int B0 = 1048576;
  const int B1 = 2621440;
  const int B2 = 2686976;
  const int B3 = 2785280;
  const int B4 = 2883584;
  const int B5 = 2949120;
  for (int i = blockIdx.x * blockDim.x + threadIdx.x; i < B5;
       i += gridDim.x * blockDim.x) {
    const float* s;
    __bf16* d;
    int off;
    if (i < B0)      { s = x;   d = xb;  off = i; }
    else if (i < B1) { s = ctx; d = cb;  off = i - B0; }
    else if (i < B2) { s = wq;  d = wqb; off = i - B1; }
    else if (i < B3) { s = wk;  d = wkb; off = i - B2; }
    else if (i < B4) { s = wv;  d = wvb; off = i - B3; }
    else             { s = wo;  d = wob; off = i - B4; }
    float4 f = ((const float4*)s)[off];
    union { __bf16 b[4]; ushort4 u; } cv;
    cv.b[0] = (__bf16)f.x; cv.b[1] = (__bf16)f.y;
    cv.b[2] = (__bf16)f.z; cv.b[3] = (__bf16)f.w;
    ((ushort4*)d)[off] = cv.u;
  }
}

// ---------------------------------------------------------------------------
// 128x128 GEMM body, glds + LDS double-buffer, ONE barrier per k-step.
// LDS layout chunked: [buf][kgrp(=w or qd)][row 0..127][8 elts = 16B].
// MODE 0 (roles swapped): bf16 out [b,h,tok,d], 8B stores over d
// MODE 1 (natural roles): bf16 out [b,h,d,tok], 8B stores over tok
// ---------------------------------------------------------------------------
template <int MODE>
__device__ __forceinline__ void gemm_body(
    const __bf16* __restrict__ A, const __bf16* __restrict__ B,
    __bf16* __restrict__ Cout, int Kd, float scale, int m0, int n0,
    __bf16 (*As)[4][128][8], __bf16 (*Bs)[4][128][8]) {
  const int t = threadIdx.x;
  const int w = t >> 6;
  const int lane = t & 63;
  const int ln = lane & 15;
  const int qd = lane >> 4;
  const int wm = (w >> 1) * 64;
  const int wn = (w & 1) * 64;

  f32x4 zero4 = {0.f, 0.f, 0.f, 0.f};
  f32x4 acc[4][4];
#pragma unroll
  for (int i = 0; i < 4; ++i)
#pragma unroll
    for (int j = 0; j < 4; ++j) acc[i][j] = zero4;

  const __bf16* gA0 = A + (size_t)(m0 + lane) * Kd + w * 8;
  const __bf16* gA1 = A + (size_t)(m0 + 64 + lane) * Kd + w * 8;
  const __bf16* gB0 = B + (size_t)(n0 + lane) * Kd + w * 8;
  const __bf16* gB1 = B + (size_t)(n0 + 64 + lane) * Kd + w * 8;

  // prologue: stage tile 0 into buf 0
  glds16(gA0, &As[0][w][0][0]);
  glds16(gA1, &As[0][w][64][0]);
  glds16(gB0, &Bs[0][w][0][0]);
  glds16(gB1, &Bs[0][w][64][0]);

  int buf = 0;
  for (int kc = 0; kc < Kd; kc += 32) {
    __syncthreads();  // drains glds(kc) [issued one full iter ago], LDS valid
    if (kc + 32 < Kd) {  // prefetch tile kc+32 into the other buffer
      glds16(gA0 + kc + 32, &As[buf ^ 1][w][0][0]);
      glds16(gA1 + kc + 32, &As[buf ^ 1][w][64][0]);
      glds16(gB0 + kc + 32, &Bs[buf ^ 1][w][0][0]);
      glds16(gB1 + kc + 32, &Bs[buf ^ 1][w][64][0]);
    }
    bf16x8 af[4], bfr[4];
#pragma unroll
    for (int i = 0; i < 4; ++i) {
      af[i] = *(const bf16x8*)&As[buf][qd][wm + i * 16 + ln][0];
      bfr[i] = *(const bf16x8*)&Bs[buf][qd][wn + i * 16 + ln][0];
    }
#pragma unroll
    for (int i = 0; i < 4; ++i)
#pragma unroll
      for (int j = 0; j < 4; ++j) {
        if (MODE == 1)
          acc[i][j] = mfma32(af[i], bfr[j], acc[i][j]);  // D: row=tok, col=e
        else
          acc[i][j] = mfma32(bfr[j], af[i], acc[i][j]);  // D: row=e, col=tok
      }
    buf ^= 1;
  }

#pragma unroll
  for (int i = 0; i < 4; ++i)
#pragma unroll
    for (int j = 0; j < 4; ++j) {
      if (MODE == 0) {
        const int gm = m0 + wm + i * 16 + ln;           // token
        const int gn0 = n0 + wn + j * 16 + qd * 4;      // e (4 consecutive)
        const int bb = gm >> 11, tok = gm & 2047;
        const int hh = gn0 >> 6, dd0 = gn0 & 63;
        bf16x4 v;
#pragma unroll
        for (int rg = 0; rg < 4; ++rg) v[rg] = (__bf16)(acc[i][j][rg] * scale);
        *(bf16x4*)(Cout + (((size_t)bb * 8 + hh) * 2048 + tok) * 64 + dd0) = v;
      } else {
        const int gm0 = m0 + wm + i * 16 + qd * 4;      // token (4 consecutive)
        const int gn = n0 + wn + j * 16 + ln;           // e
        const int bb = gm0 >> 11, tok0 = gm0 & 2047;
        const int hh = gn >> 6, dd = gn & 63;
        bf16x4 v;
#pragma unroll
        for (int rg = 0; rg < 4; ++rg) v[rg] = (__bf16)acc[i][j][rg];
        *(bf16x4*)(Cout + (((size_t)bb * 8 + hh) * 64 + dd) * 2048 + tok0) = v;
      }
    }
}

// Fused Q/K/V projections: grid (64, 12) = 768 blocks -> 3 blocks/CU.
// LDS: 2 bufs x (A 8KB + B 8KB) = 32KB.
__global__ __launch_bounds__(256, 3) void proj_qkv(
    const __bf16* __restrict__ xb, const __bf16* __restrict__ cb,
    const __bf16* __restrict__ Wq, const __bf16* __restrict__ Wk,
    const __bf16* __restrict__ Wv, __bf16* __restrict__ Qw,
    __bf16* __restrict__ Kw, __bf16* __restrict__ Vtw) {
  __shared__ __align__(16) __bf16 As[2][4][128][8];
  __shared__ __align__(16) __bf16 Bs[2][4][128][8];
  const int m0 = blockIdx.x * 128;
  const int job = blockIdx.y >> 2;  // 0=Q, 1=K, 2=V
  const int n0 = (blockIdx.y & 3) * 128;
  if (job == 0)
    gemm_body<0>(xb, Wq, Qw, 512, QSCALE, m0, n0, As, Bs);
  else if (job == 1)
    gemm_body<0>(cb, Wk, Kw, 768, 1.0f, m0, n0, As, Bs);
  else
    gemm_body<1>(cb, Wv, Vtw, 768, 1.0f, m0, n0, As, Bs);
}

// ---------------------------------------------------------------------------
// Final GEMM: out = ((O0+O1)/(l0+l1)) Wo^T + bo, fp32.  64x128 tiles,
// grid (128,4)=512.  Single-barrier pipeline: A (combine) manual dbuf,
// B glds dbuf.  inv(l) hoisted.
// ---------------------------------------------------------------------------
__global__ __launch_bounds__(256) void gemm_out(
    const __bf16* __restrict__ O0, const __bf16* __restrict__ O1,
    const float* __restrict__ lbuf,  // [2][32][2048]
    const __bf16* __restrict__ B,    // Wo bf16 [512 x 512]
    float* __restrict__ C, const float* __restrict__ bias) {
  const int m0 = blockIdx.x * 64;
  const int n0 = blockIdx.y * 128;
  const int t = threadIdx.x;
  const int w = t >> 6;
  const int lane = t & 63;
  const int ln = lane & 15;
  const int qd = lane >> 4;
  const int wm = (w >> 1) * 32;
  const int wn = (w & 1) * 64;

  __shared__ __align__(16) __bf16 As[2][64][40];     // manual, padded
  __shared__ __align__(16) __bf16 Bs[2][4][128][8];  // glds, chunked

  f32x4 zero4 = {0.f, 0.f, 0.f, 0.f};
  f32x4 acc[2][4];
#pragma unroll
  for (int i = 0; i < 2; ++i)
#pragma unroll
    for (int j = 0; j < 4; ++j) acc[i][j] = zero4;

  const int ra = t >> 2, ca = (t & 3) * 8;  // A staging: 8 elts/thread
  const int gm_s = m0 + ra;
  const int bidx = gm_s >> 11, tok_s = gm_s & 2047;
  const size_t aoff = (size_t)gm_s * 512 + ca;
  const __bf16* gB0 = B + (size_t)(n0 + lane) * 512 + w * 8;
  const __bf16* gB1 = B + (size_t)(n0 + 64 + lane) * 512 + w * 8;

  // hoist the split-l combine out of the k-loop
  float inv[8];
#pragma unroll
  for (int hh = 0; hh < 8; ++hh) {
    const float l0 = lbuf[((size_t)bidx * 8 + hh) * 2048 + tok_s];
    const float l1 = lbuf[65536 + ((size_t)bidx * 8 + hh) * 2048 + tok_s];
    inv[hh] = 1.0f / (l0 + l1);
  }

  // prologue: tile 0 -> buf 0 (A manual combine, B glds)
  {
    union { bf16x8 v; uint4 u; } u0, u1, rr;
    u0.u = *(const uint4*)(O0 + aoff);
    u1.u = *(const uint4*)(O1 + aoff);
    glds16(gB0, &Bs[0][w][0][0]);
    glds16(gB1, &Bs[0][w][64][0]);
    const float iv = inv[0];
#pragma unroll
    for (int e = 0; e < 8; ++e)
      rr.v[e] = (__bf16)(((float)u0.v[e] + (float)u1.v[e]) * iv);
    *(uint4*)&As[0][ra][ca] = rr.u;
  }

  int buf = 0;
#pragma unroll
  for (int k = 0; k < 16; ++k) {
    __syncthreads();  // tile-k As writes + B glds visible
    uint4 o0n, o1n;
    if (k < 15) {  // issue next-tile loads early (covered by MFMAs)
      o0n = *(const uint4*)(O0 + aoff + (k + 1) * 32);
      o1n = *(const uint4*)(O1 + aoff + (k + 1) * 32);
      glds16(gB0 + (k + 1) * 32, &Bs[buf ^ 1][w][0][0]);
      glds16(gB1 + (k + 1) * 32, &Bs[buf ^ 1][w][64][0]);
    }
    bf16x8 af[2], bfr[4];
#pragma unroll
    for (int i = 0; i < 2; ++i)
      af[i] = *(const bf16x8*)&As[buf][wm + i * 16 + ln][qd * 8];
#pragma unroll
    for (int j = 0; j < 4; ++j)
      bfr[j] = *(const bf16x8*)&Bs[buf][qd][wn + j * 16 + ln][0];
#pragma unroll
    for (int i = 0; i < 2; ++i)
#pragma unroll
      for (int j = 0; j < 4; ++j)
        acc[i][j] = mfma32(bfr[j], af[i], acc[i][j]);
    if (k < 15) {  // combine + write next A tile into the other buffer
      union { bf16x8 v; uint4 u; } u0, u1, rr;
      u0.u = o0n;
      u1.u = o1n;
      const float iv = inv[(k + 1) >> 1];
#pragma unroll
      for (int e = 0; e < 8; ++e)
        rr.v[e] = (__bf16)(((float)u0.v[e] + (float)u1.v[e]) * iv);
      *(uint4*)&As[buf ^ 1][ra][ca] = rr.u;
    }
    buf ^= 1;
  }

#pragma unroll
  for (int i = 0; i < 2; ++i)
#pragma unroll
    for (int j = 0; j < 4; ++j) {
      const int gm = m0 + wm + i * 16 + ln;
      const int gn0 = n0 + wn + j * 16 + qd * 4;
      f32x4 bi = *(const f32x4*)&bias[gn0];
      f32x4 v = acc[i][j] + bi;
      *(f32x4*)&C[(size_t)gm * 512 + gn0] = v;
    }
}

// ---------------------------------------------------------------------------
// Flash attention: S^T trick, raw-exp2 max-free softmax, BQ=128, split-K=2.
// Q in registers; Ks[128][72] b128 frags; Vts[64][132] b64 frags (the
// 3.1M-conflict config).  l accumulated ON THE MFMA PIPE via all-ones A-frag
// (V-ones trick) -> no VALU adds, no epilogue shuffles.
// ---------------------------------------------------------------------------
__global__ __launch_bounds__(256, 4) void attn_kernel(
    const __bf16* __restrict__ Q,   // [BH][2048][64], pre-scaled by QSCALE
    const __bf16* __restrict__ K,   // [BH][2048][64]
    const __bf16* __restrict__ Vt,  // [BH][64][2048]
    __bf16* __restrict__ Oh,        // [2][B][2048][512] unnormalized
    float* __restrict__ lbuf) {     // [2][BH][2048]
  const int S = 2048;
  const int qt = blockIdx.x;
  const int bh = blockIdx.y;
  const int sp = blockIdx.z;
  const int b = bh >> 3, h = bh & 7;
  const int t = threadIdx.x;
  const int w = t >> 6;
  const int lane = t & 63;
  const int ln = lane & 15;
  const int qd = lane >> 4;

  __shared__ __align__(16) __bf16 Ks[128][72];   // 18432B
  __shared__ __align__(16) __bf16 Vts[64][132];  // 16896B  total 35328B

  // ---- Q fragments in registers (wave w owns Q rows w*32 .. w*32+31)
  bf16x8 bq[2][2];  // [mt][kst]
  {
    const __bf16* qb =
        Q + ((size_t)bh * S + qt * 128 + w * 32 + ln) * 64 + qd * 8;
#pragma unroll
    for (int mt = 0; mt < 2; ++mt)
#pragma unroll
      for (int kst = 0; kst < 2; ++kst)
        bq[mt][kst] = *(const bf16x8*)(qb + mt * 1024 + kst * 32);
  }

  f32x4 zero4 = {0.f, 0.f, 0.f, 0.f};
  f32x4 o[2][4];   // o[mt][i]: D[row=d=i*16+qd*4+rg][col=Qrow=ln]
  f32x4 o_l[2];    // V-ones row-sum accumulator: all regs = l(Qrow=ln)
#pragma unroll
  for (int mt = 0; mt < 2; ++mt) {
#pragma unroll
    for (int i = 0; i < 4; ++i) o[mt][i] = zero4;
    o_l[mt] = zero4;
  }
  const s16x4 ones = {0x3F80, 0x3F80, 0x3F80, 0x3F80};  // bf16 1.0 x4

  const int kr = t >> 1, kc = (t & 1) * 32;  // K staging map
  const int vd = t >> 2, vc = (t & 3) * 32;  // Vt staging map
  const int kt0 = sp * 8;

  for (int kt = kt0; kt < kt0 + 8; ++kt) {
    const uint4* gK =
        (const uint4*)(K + ((size_t)bh * S + kt * 128 + kr) * 64 + kc);
    const uint4* gV =
        (const uint4*)(Vt + ((size_t)bh * 64 + vd) * S + kt * 128 + vc);
    uint4 kv0 = gK[0], kv1 = gK[1], kv2 = gK[2], kv3 = gK[3];
    uint4 vv0 = gV[0], vv1 = gV[1], vv2 = gV[2], vv3 = gV[3];
    __syncthreads();
    {
      uint4* dK = (uint4*)&Ks[kr][kc];   // 144B stride: 16B-aligned
      dK[0] = kv0; dK[1] = kv1; dK[2] = kv2; dK[3] = kv3;
      uint2* dV = (uint2*)&Vts[vd][vc];  // 264B stride: 8B-aligned
      dV[0] = *(uint2*)&vv0; dV[1] = *((uint2*)&vv0 + 1);
      dV[2] = *(uint2*)&vv1; dV[3] = *((uint2*)&vv1 + 1);
      dV[4] = *(uint2*)&vv2; dV[5] = *((uint2*)&vv2 + 1);
      dV[6] = *(uint2*)&vv3; dV[7] = *((uint2*)&vv3 + 1);
    }
    __syncthreads();

    // ---- per nt-pair: QK (mfma32) -> exp2 -> PV (mfma16) + ones row-sum
#pragma unroll
    for (int c = 0; c < 4; ++c) {
      f32x4 s[2][2];  // [e][mt]
      s[0][0] = zero4; s[0][1] = zero4; s[1][0] = zero4; s[1][1] = zero4;
#pragma unroll
      for (int e = 0; e < 2; ++e) {
        const int nt = c * 2 + e;
#pragma unroll
        for (int kst = 0; kst < 2; ++kst) {
          bf16x8 ak = *(const bf16x8*)&Ks[nt * 16 + ln][kst * 32 + qd * 8];
          s[e][0] = mfma32(ak, bq[0][kst], s[e][0]);
          s[e][1] = mfma32(ak, bq[1][kst], s[e][1]);
        }
      }
      // max-free softmax: P = 2^s (raw v_exp_f32; s bounded well above -126)
#pragma unroll
      for (int e = 0; e < 2; ++e)
#pragma unroll
        for (int mt = 0; mt < 2; ++mt)
#pragma unroll
          for (int rg = 0; rg < 4; ++rg) s[e][mt][rg] = EXP2(s[e][mt][rg]);
      // pack -> PV + l-accumulation on the MFMA pipe
#pragma unroll
      for (int e = 0; e < 2; ++e) {
        const int nt = c * 2 + e;
        bf16x4 c0, c1;
#pragma unroll
        for (int rg = 0; rg < 4; ++rg) {
          c0[rg] = (__bf16)s[e][0][rg];
          c1[rg] = (__bf16)s[e][1][rg];
        }
        s16x4 p0 = __builtin_bit_cast(s16x4, c0);
        s16x4 p1 = __builtin_bit_cast(s16x4, c1);
        o_l[0] = mfma16(ones, p0, o_l[0]);
        o_l[1] = mfma16(ones, p1, o_l[1]);
#pragma unroll
        for (int i = 0; i < 4; ++i) {
          bf16x4 av = *(const bf16x4*)&Vts[i * 16 + ln][nt * 16 + qd * 4];
          s16x4 a = __builtin_bit_cast(s16x4, av);
          o[0][i] = mfma16(a, p0, o[0][i]);
          o[1][i] = mfma16(a, p1, o[1][i]);
        }
      }
    }
  }

  // ---- epilogue: write UNNORMALIZED O + l (combine happens in gemm_out)
  __bf16* Osp = Oh + (size_t)sp * 8192 * 512;
#pragma unroll
  for (int mt = 0; mt < 2; ++mt) {
    const int tok = qt * 128 + w * 32 + mt * 16 + ln;
    if (qd == 0) lbuf[((size_t)sp * 32 + bh) * 2048 + tok] = o_l[mt][0];
#pragma unroll
    for (int i = 0; i < 4; ++i) {
      bf16x4 v;
#pragma unroll
      for (int rg = 0; rg < 4; ++rg) v[rg] = (__bf16)o[mt][i][rg];
      const int col = h * 64 + i * 16 + qd * 4;
      *(bf16x4*)&Osp[((size_t)b * S + tok) * 512 + col] = v;
    }
  }
}

// ---------------------------------------------------------------------------
extern "C" void kernel_launch(void* const* d_in, const int* in_sizes, int n_in,
                              void* d_out, int out_size, void* d_ws,
                              size_t ws_size, hipStream_t stream) {
  const float* x = (const float*)d_in[0];
  const float* ctx = (const float*)d_in[1];
  const float* Wq = (const float*)d_in[2];
  const float* Wk = (const float*)d_in[3];
  const float* Wv = (const float*)d_in[4];
  const float* Wo = (const float*)d_in[5];
  const float* bo = (const float*)d_in[6];

  char* p = (char*)d_ws;
  __bf16* xb = (__bf16*)p;   p += (size_t)8192 * 512 * 2;
  __bf16* cb = (__bf16*)p;   p += (size_t)8192 * 768 * 2;
  __bf16* wqb = (__bf16*)p;  p += (size_t)512 * 512 * 2;
  __bf16* wkb = (__bf16*)p;  p += (size_t)512 * 768 * 2;
  __bf16* wvb = (__bf16*)p;  p += (size_t)512 * 768 * 2;
  __bf16* wob = (__bf16*)p;  p += (size_t)512 * 512 * 2;
  __bf16* Qw = (__bf16*)p;   p += (size_t)8192 * 512 * 2;
  __bf16* Kw = (__bf16*)p;   p += (size_t)8192 * 512 * 2;
  __bf16* Vtw = (__bf16*)p;  p += (size_t)8192 * 512 * 2;
  __bf16* Oh = (__bf16*)p;   p += (size_t)2 * 8192 * 512 * 2;
  float* lbuf = (float*)p;   p += (size_t)2 * 32 * 2048 * 4;

  cast_all<<<2880, 256, 0, stream>>>(x, ctx, Wq, Wk, Wv, Wo, xb, cb, wqb, wkb,
                                     wvb, wob);

  dim3 gp(64, 12);
  proj_qkv<<<gp, 256, 0, stream>>>(xb, cb, wqb, wkb, wvb, Qw, Kw, Vtw);

  dim3 ga(16, 32, 2);
  attn_kernel<<<ga, 256, 0, stream>>>(Qw, Kw, Vtw, Oh, lbuf);

  dim3 go(128, 4);
  gemm_out<<<go, 256, 0, stream>>>(Oh, Oh + (size_t)8192 * 512, lbuf, wob,
                                   (float*)d_out, bo);
}

// Round 9
// 202.595 us; speedup vs baseline: 1.0714x; 1.0070x over previous
//
#include <hip/hip_runtime.h>
#include <hip/hip_bf16.h>
#include <math.h>

// ---------------------------------------------------------------------------
// CrossAttention on MI355X (gfx950), bf16 MFMA pipeline, round 9.
//   cast_all: fp32 -> bf16 (BW-bound pass)
//   proj_qkv: manual 2-barrier staging, BM=64 -> 1536 blocks = 6/CU
//   attn: R8 kernel unchanged (BQ=128 split-K=2, Q in regs, S^T trick,
//         raw v_exp_f32 max-free softmax, V-ones MFMA row-sum) - 52.6us
//   gemm_out: manual staging, 64x64 tiles -> 1024 blocks = 4/CU, inv hoisted
// ---------------------------------------------------------------------------

typedef __bf16 bf16x8 __attribute__((ext_vector_type(8)));
typedef __bf16 bf16x4 __attribute__((ext_vector_type(4)));
typedef short s16x4 __attribute__((ext_vector_type(4)));
typedef float f32x4 __attribute__((ext_vector_type(4)));

#define QSCALE 0.18033688011112042f  // 0.125 * log2(e)

#if __has_builtin(__builtin_amdgcn_exp2f)
#define EXP2(x) __builtin_amdgcn_exp2f(x)
#else
#define EXP2(x) exp2f(x)
#endif

__device__ __forceinline__ f32x4 mfma32(bf16x8 a, bf16x8 b, f32x4 c) {
  // 16x16x32: A[m=ln][k=qd*8+j], B[n=ln][k=qd*8+j], D: col=ln, row=qd*4+reg
  return __builtin_amdgcn_mfma_f32_16x16x32_bf16(a, b, c, 0, 0, 0);
}
__device__ __forceinline__ f32x4 mfma16(s16x4 a, s16x4 b, f32x4 c) {
  // 16x16x16: A[m=ln][k=qd*4+j], B[n=ln][k=qd*4+j], D: col=ln, row=qd*4+reg
  return __builtin_amdgcn_mfma_f32_16x16x16bf16_1k(a, b, c, 0, 0, 0);
}

// ---------------------------------------------------------------------------
// fp32 -> bf16 cast of all inputs.
// ---------------------------------------------------------------------------
__global__ __launch_bounds__(256) void cast_all(
    const float* __restrict__ x, const float* __restrict__ ctx,
    const float* __restrict__ wq, const float* __restrict__ wk,
    const float* __restrict__ wv, const float* __restrict__ wo,
    __bf16* __restrict__ xb, __bf16* __restrict__ cb,
    __bf16* __restrict__ wqb, __bf16* __restrict__ wkb,
    __bf16* __restrict__ wvb, __bf16* __restrict__ wob) {
  const int B0 = 1048576;
  const int B1 = 2621440;
  const int B2 = 2686976;
  const int B3 = 2785280;
  const int B4 = 2883584;
  const int B5 = 2949120;
  for (int i = blockIdx.x * blockDim.x + threadIdx.x; i < B5;
       i += gridDim.x * blockDim.x) {
    const float* s;
    __bf16* d;
    int off;
    if (i < B0)      { s = x;   d = xb;  off = i; }
    else if (i < B1) { s = ctx; d = cb;  off = i - B0; }
    else if (i < B2) { s = wq;  d = wqb; off = i - B1; }
    else if (i < B3) { s = wk;  d = wkb; off = i - B2; }
    else if (i < B4) { s = wv;  d = wvb; off = i - B3; }
    else             { s = wo;  d = wob; off = i - B4; }
    float4 f = ((const float4*)s)[off];
    union { __bf16 b[4]; ushort4 u; } cv;
    cv.b[0] = (__bf16)f.x; cv.b[1] = (__bf16)f.y;
    cv.b[2] = (__bf16)f.z; cv.b[3] = (__bf16)f.w;
    ((ushort4*)d)[off] = cv.u;
  }
}

// ---------------------------------------------------------------------------
// 64x128 GEMM body, manual 2-barrier staging, bf16 inputs.
// 4 waves as 2x2 of 32x64.  Per k-iter: 8 mfma32.
// MODE 0 (roles swapped): bf16 out [b,h,tok,d], 8B stores over d
// MODE 1 (natural roles): bf16 out [b,h,d,tok], 8B stores over tok
// ---------------------------------------------------------------------------
template <int MODE>
__device__ __forceinline__ void gemm_body64(
    const __bf16* __restrict__ A, const __bf16* __restrict__ B,
    __bf16* __restrict__ Cout, int Kd, float scale, int m0, int n0,
    __bf16 (*As)[40], __bf16 (*Bs)[40]) {
  const int t = threadIdx.x;
  const int w = t >> 6;
  const int lane = t & 63;
  const int ln = lane & 15;
  const int qd = lane >> 4;
  const int wm = (w >> 1) * 32;
  const int wn = (w & 1) * 64;

  f32x4 zero4 = {0.f, 0.f, 0.f, 0.f};
  f32x4 acc[2][4];
#pragma unroll
  for (int i = 0; i < 2; ++i)
#pragma unroll
    for (int j = 0; j < 4; ++j) acc[i][j] = zero4;

  const int ra = t >> 2, ca = (t & 3) * 8;   // A: 64x32, one uint4/thread
  const int rb = t >> 1, cbx = (t & 1) * 16; // B: 128x32, two uint4/thread
  const __bf16* gA = A + (size_t)(m0 + ra) * Kd + ca;
  const __bf16* gB = B + (size_t)(n0 + rb) * Kd + cbx;

  for (int kc = 0; kc < Kd; kc += 32) {
    uint4 a0 = *(const uint4*)(gA + kc);
    uint4 b0 = *(const uint4*)(gB + kc);
    uint4 b1 = *(const uint4*)(gB + kc + 8);
    __syncthreads();
    *(uint4*)&As[ra][ca] = a0;
    *(uint4*)&Bs[rb][cbx] = b0;
    *(uint4*)&Bs[rb][cbx + 8] = b1;
    __syncthreads();
    bf16x8 af[2], bfr[4];
#pragma unroll
    for (int i = 0; i < 2; ++i)
      af[i] = *(const bf16x8*)&As[wm + i * 16 + ln][qd * 8];
#pragma unroll
    for (int j = 0; j < 4; ++j)
      bfr[j] = *(const bf16x8*)&Bs[wn + j * 16 + ln][qd * 8];
#pragma unroll
    for (int i = 0; i < 2; ++i)
#pragma unroll
      for (int j = 0; j < 4; ++j) {
        if (MODE == 1)
          acc[i][j] = mfma32(af[i], bfr[j], acc[i][j]);  // D: row=tok, col=e
        else
          acc[i][j] = mfma32(bfr[j], af[i], acc[i][j]);  // D: row=e, col=tok
      }
  }

#pragma unroll
  for (int i = 0; i < 2; ++i)
#pragma unroll
    for (int j = 0; j < 4; ++j) {
      if (MODE == 0) {
        const int gm = m0 + wm + i * 16 + ln;           // token
        const int gn0 = n0 + wn + j * 16 + qd * 4;      // e (4 consecutive)
        const int bb = gm >> 11, tok = gm & 2047;
        const int hh = gn0 >> 6, dd0 = gn0 & 63;
        bf16x4 v;
#pragma unroll
        for (int rg = 0; rg < 4; ++rg) v[rg] = (__bf16)(acc[i][j][rg] * scale);
        *(bf16x4*)(Cout + (((size_t)bb * 8 + hh) * 2048 + tok) * 64 + dd0) = v;
      } else {
        const int gm0 = m0 + wm + i * 16 + qd * 4;      // token (4 consecutive)
        const int gn = n0 + wn + j * 16 + ln;           // e
        const int bb = gm0 >> 11, tok0 = gm0 & 2047;
        const int hh = gn >> 6, dd = gn & 63;
        bf16x4 v;
#pragma unroll
        for (int rg = 0; rg < 4; ++rg) v[rg] = (__bf16)acc[i][j][rg];
        *(bf16x4*)(Cout + (((size_t)bb * 8 + hh) * 64 + dd) * 2048 + tok0) = v;
      }
    }
}

// Fused Q/K/V projections: grid (128, 12) = 1536 blocks -> 6 blocks/CU.
__global__ __launch_bounds__(256, 4) void proj_qkv(
    const __bf16* __restrict__ xb, const __bf16* __restrict__ cb,
    const __bf16* __restrict__ Wq, const __bf16* __restrict__ Wk,
    const __bf16* __restrict__ Wv, __bf16* __restrict__ Qw,
    __bf16* __restrict__ Kw, __bf16* __restrict__ Vtw) {
  __shared__ __bf16 As[64][40];    // 5120B
  __shared__ __bf16 Bs[128][40];   // 10240B  -> 15.4KB total
  const int m0 = blockIdx.x * 64;
  const int job = blockIdx.y >> 2;  // 0=Q, 1=K, 2=V
  const int n0 = (blockIdx.y & 3) * 128;
  if (job == 0)
    gemm_body64<0>(xb, Wq, Qw, 512, QSCALE, m0, n0, As, Bs);
  else if (job == 1)
    gemm_body64<0>(cb, Wk, Kw, 768, 1.0f, m0, n0, As, Bs);
  else
    gemm_body64<1>(cb, Wv, Vtw, 768, 1.0f, m0, n0, As, Bs);
}

// ---------------------------------------------------------------------------
// Final GEMM: out = ((O0+O1)/(l0+l1)) Wo^T + bo, fp32.  64x64 tiles,
// grid (128,8) = 1024 blocks -> 4 blocks/CU.  Manual 2-barrier staging;
// inv(l) hoisted out of the k-loop.
// ---------------------------------------------------------------------------
__global__ __launch_bounds__(256, 4) void gemm_out(
    const __bf16* __restrict__ O0, const __bf16* __restrict__ O1,
    const float* __restrict__ lbuf,  // [2][32][2048]
    const __bf16* __restrict__ B,    // Wo bf16 [512 x 512]
    float* __restrict__ C, const float* __restrict__ bias) {
  const int m0 = blockIdx.x * 64;
  const int n0 = blockIdx.y * 64;
  const int t = threadIdx.x;
  const int w = t >> 6;
  const int lane = t & 63;
  const int ln = lane & 15;
  const int qd = lane >> 4;
  const int wm = (w >> 1) * 32;
  const int wn = (w & 1) * 32;

  __shared__ __bf16 As[64][40];  // 5120B
  __shared__ __bf16 Bs[64][40];  // 5120B

  f32x4 zero4 = {0.f, 0.f, 0.f, 0.f};
  f32x4 acc[2][2];
#pragma unroll
  for (int i = 0; i < 2; ++i)
#pragma unroll
    for (int j = 0; j < 2; ++j) acc[i][j] = zero4;

  const int ra = t >> 2, ca = (t & 3) * 8;  // both tiles: 64x32, uint4/thread
  const int gm_s = m0 + ra;
  const int bidx = gm_s >> 11, tok_s = gm_s & 2047;
  const size_t aoff = (size_t)gm_s * 512 + ca;
  const __bf16* gB = B + (size_t)(n0 + ra) * 512 + ca;

  // hoist the split-l combine out of the k-loop
  float inv[8];
#pragma unroll
  for (int hh = 0; hh < 8; ++hh) {
    const float l0 = lbuf[((size_t)bidx * 8 + hh) * 2048 + tok_s];
    const float l1 = lbuf[65536 + ((size_t)bidx * 8 + hh) * 2048 + tok_s];
    inv[hh] = 1.0f / (l0 + l1);
  }

  for (int kc = 0; kc < 512; kc += 32) {
    const float iv = inv[kc >> 6];
    union { bf16x8 v; uint4 u; } u0, u1, rr;
    u0.u = *(const uint4*)(O0 + aoff + kc);
    u1.u = *(const uint4*)(O1 + aoff + kc);
    uint4 bv = *(const uint4*)(gB + kc);
#pragma unroll
    for (int e = 0; e < 8; ++e)
      rr.v[e] = (__bf16)(((float)u0.v[e] + (float)u1.v[e]) * iv);
    __syncthreads();
    *(uint4*)&As[ra][ca] = rr.u;
    *(uint4*)&Bs[ra][ca] = bv;
    __syncthreads();
    bf16x8 af[2], bfr[2];
#pragma unroll
    for (int i = 0; i < 2; ++i)
      af[i] = *(const bf16x8*)&As[wm + i * 16 + ln][qd * 8];
#pragma unroll
    for (int j = 0; j < 2; ++j)
      bfr[j] = *(const bf16x8*)&Bs[wn + j * 16 + ln][qd * 8];
#pragma unroll
    for (int i = 0; i < 2; ++i)
#pragma unroll
      for (int j = 0; j < 2; ++j)
        acc[i][j] = mfma32(bfr[j], af[i], acc[i][j]);  // D: row=e, col=tok
  }

#pragma unroll
  for (int i = 0; i < 2; ++i)
#pragma unroll
    for (int j = 0; j < 2; ++j) {
      const int gm = m0 + wm + i * 16 + ln;
      const int gn0 = n0 + wn + j * 16 + qd * 4;
      f32x4 bi = *(const f32x4*)&bias[gn0];
      f32x4 v = acc[i][j] + bi;
      *(f32x4*)&C[(size_t)gm * 512 + gn0] = v;
    }
}

// ---------------------------------------------------------------------------
// Flash attention: R8 kernel unchanged (verified 52.6us, MfmaUtil 45%).
// S^T trick, raw-exp2 max-free softmax, BQ=128, split-K=2, Q in regs,
// V-ones MFMA row-sum.
// ---------------------------------------------------------------------------
__global__ __launch_bounds__(256, 4) void attn_kernel(
    const __bf16* __restrict__ Q,   // [BH][2048][64], pre-scaled by QSCALE
    const __bf16* __restrict__ K,   // [BH][2048][64]
    const __bf16* __restrict__ Vt,  // [BH][64][2048]
    __bf16* __restrict__ Oh,        // [2][B][2048][512] unnormalized
    float* __restrict__ lbuf) {     // [2][BH][2048]
  const int S = 2048;
  const int qt = blockIdx.x;
  const int bh = blockIdx.y;
  const int sp = blockIdx.z;
  const int b = bh >> 3, h = bh & 7;
  const int t = threadIdx.x;
  const int w = t >> 6;
  const int lane = t & 63;
  const int ln = lane & 15;
  const int qd = lane >> 4;

  __shared__ __align__(16) __bf16 Ks[128][72];   // 18432B
  __shared__ __align__(16) __bf16 Vts[64][132];  // 16896B  total 35328B

  bf16x8 bq[2][2];  // [mt][kst]
  {
    const __bf16* qb =
        Q + ((size_t)bh * S + qt * 128 + w * 32 + ln) * 64 + qd * 8;
#pragma unroll
    for (int mt = 0; mt < 2; ++mt)
#pragma unroll
      for (int kst = 0; kst < 2; ++kst)
        bq[mt][kst] = *(const bf16x8*)(qb + mt * 1024 + kst * 32);
  }

  f32x4 zero4 = {0.f, 0.f, 0.f, 0.f};
  f32x4 o[2][4];
  f32x4 o_l[2];
#pragma unroll
  for (int mt = 0; mt < 2; ++mt) {
#pragma unroll
    for (int i = 0; i < 4; ++i) o[mt][i] = zero4;
    o_l[mt] = zero4;
  }
  const s16x4 ones = {0x3F80, 0x3F80, 0x3F80, 0x3F80};  // bf16 1.0 x4

  const int kr = t >> 1, kc = (t & 1) * 32;
  const int vd = t >> 2, vc = (t & 3) * 32;
  const int kt0 = sp * 8;

  for (int kt = kt0; kt < kt0 + 8; ++kt) {
    const uint4* gK =
        (const uint4*)(K + ((size_t)bh * S + kt * 128 + kr) * 64 + kc);
    const uint4* gV =
        (const uint4*)(Vt + ((size_t)bh * 64 + vd) * S + kt * 128 + vc);
    uint4 kv0 = gK[0], kv1 = gK[1], kv2 = gK[2], kv3 = gK[3];
    uint4 vv0 = gV[0], vv1 = gV[1], vv2 = gV[2], vv3 = gV[3];
    __syncthreads();
    {
      uint4* dK = (uint4*)&Ks[kr][kc];
      dK[0] = kv0; dK[1] = kv1; dK[2] = kv2; dK[3] = kv3;
      uint2* dV = (uint2*)&Vts[vd][vc];
      dV[0] = *(uint2*)&vv0; dV[1] = *((uint2*)&vv0 + 1);
      dV[2] = *(uint2*)&vv1; dV[3] = *((uint2*)&vv1 + 1);
      dV[4] = *(uint2*)&vv2; dV[5] = *((uint2*)&vv2 + 1);
      dV[6] = *(uint2*)&vv3; dV[7] = *((uint2*)&vv3 + 1);
    }
    __syncthreads();

#pragma unroll
    for (int c = 0; c < 4; ++c) {
      f32x4 s[2][2];  // [e][mt]
      s[0][0] = zero4; s[0][1] = zero4; s[1][0] = zero4; s[1][1] = zero4;
#pragma unroll
      for (int e = 0; e < 2; ++e) {
        const int nt = c * 2 + e;
#pragma unroll
        for (int kst = 0; kst < 2; ++kst) {
          bf16x8 ak = *(const bf16x8*)&Ks[nt * 16 + ln][kst * 32 + qd * 8];
          s[e][0] = mfma32(ak, bq[0][kst], s[e][0]);
          s[e][1] = mfma32(ak, bq[1][kst], s[e][1]);
        }
      }
#pragma unroll
      for (int e = 0; e < 2; ++e)
#pragma unroll
        for (int mt = 0; mt < 2; ++mt)
#pragma unroll
          for (int rg = 0; rg < 4; ++rg) s[e][mt][rg] = EXP2(s[e][mt][rg]);
#pragma unroll
      for (int e = 0; e < 2; ++e) {
        const int nt = c * 2 + e;
        bf16x4 c0, c1;
#pragma unroll
        for (int rg = 0; rg < 4; ++rg) {
          c0[rg] = (__bf16)s[e][0][rg];
          c1[rg] = (__bf16)s[e][1][rg];
        }
        s16x4 p0 = __builtin_bit_cast(s16x4, c0);
        s16x4 p1 = __builtin_bit_cast(s16x4, c1);
        o_l[0] = mfma16(ones, p0, o_l[0]);
        o_l[1] = mfma16(ones, p1, o_l[1]);
#pragma unroll
        for (int i = 0; i < 4; ++i) {
          bf16x4 av = *(const bf16x4*)&Vts[i * 16 + ln][nt * 16 + qd * 4];
          s16x4 a = __builtin_bit_cast(s16x4, av);
          o[0][i] = mfma16(a, p0, o[0][i]);
          o[1][i] = mfma16(a, p1, o[1][i]);
        }
      }
    }
  }

  __bf16* Osp = Oh + (size_t)sp * 8192 * 512;
#pragma unroll
  for (int mt = 0; mt < 2; ++mt) {
    const int tok = qt * 128 + w * 32 + mt * 16 + ln;
    if (qd == 0) lbuf[((size_t)sp * 32 + bh) * 2048 + tok] = o_l[mt][0];
#pragma unroll
    for (int i = 0; i < 4; ++i) {
      bf16x4 v;
#pragma unroll
      for (int rg = 0; rg < 4; ++rg) v[rg] = (__bf16)o[mt][i][rg];
      const int col = h * 64 + i * 16 + qd * 4;
      *(bf16x4*)&Osp[((size_t)b * S + tok) * 512 + col] = v;
    }
  }
}

// ---------------------------------------------------------------------------
extern "C" void kernel_launch(void* const* d_in, const int* in_sizes, int n_in,
                              void* d_out, int out_size, void* d_ws,
                              size_t ws_size, hipStream_t stream) {
  const float* x = (const float*)d_in[0];
  const float* ctx = (const float*)d_in[1];
  const float* Wq = (const float*)d_in[2];
  const float* Wk = (const float*)d_in[3];
  const float* Wv = (const float*)d_in[4];
  const float* Wo = (const float*)d_in[5];
  const float* bo = (const float*)d_in[6];

  char* p = (char*)d_ws;
  __bf16* xb = (__bf16*)p;   p += (size_t)8192 * 512 * 2;
  __bf16* cb = (__bf16*)p;   p += (size_t)8192 * 768 * 2;
  __bf16* wqb = (__bf16*)p;  p += (size_t)512 * 512 * 2;
  __bf16* wkb = (__bf16*)p;  p += (size_t)512 * 768 * 2;
  __bf16* wvb = (__bf16*)p;  p += (size_t)512 * 768 * 2;
  __bf16* wob = (__bf16*)p;  p += (size_t)512 * 512 * 2;
  __bf16* Qw = (__bf16*)p;   p += (size_t)8192 * 512 * 2;
  __bf16* Kw = (__bf16*)p;   p += (size_t)8192 * 512 * 2;
  __bf16* Vtw = (__bf16*)p;  p += (size_t)8192 * 512 * 2;
  __bf16* Oh = (__bf16*)p;   p += (size_t)2 * 8192 * 512 * 2;
  float* lbuf = (float*)p;   p += (size_t)2 * 32 * 2048 * 4;

  cast_all<<<2880, 256, 0, stream>>>(x, ctx, Wq, Wk, Wv, Wo, xb, cb, wqb, wkb,
                                     wvb, wob);

  dim3 gp(128, 12);
  proj_qkv<<<gp, 256, 0, stream>>>(xb, cb, wqb, wkb, wvb, Qw, Kw, Vtw);

  dim3 ga(16, 32, 2);
  attn_kernel<<<ga, 256, 0, stream>>>(Qw, Kw, Vtw, Oh, lbuf);

  dim3 go(128, 8);
  gemm_out<<<go, 256, 0, stream>>>(Oh, Oh + (size_t)8192 * 512, lbuf, wob,
                                   (float*)d_out, bo);
}